// Round 1
// baseline (431.679 us; speedup 1.0000x reference)
//
#include <hip/hip_runtime.h>

// KernelAggregation: per-sample mixed 3x3 SAME conv, implicit GEMM via bf16 MFMA.
// ws layout: [0, 2359296) = w_mix bf16 [32][64][9][64]; [2359296, +8192) = b_mix f32 [32][64].

#define DIM 64
#define BATCH 32
#define HH 128
#define WW 128
#define NK 4

typedef __attribute__((ext_vector_type(4))) float f32x4;
typedef __attribute__((ext_vector_type(8))) short bf16x8;
typedef __attribute__((ext_vector_type(8))) unsigned short ushort8;

static __device__ __forceinline__ unsigned short f2bf(float f) {
    union { float f; unsigned u; } v; v.f = f;
    unsigned r = v.u + 0x7fffu + ((v.u >> 16) & 1u);   // RNE, inputs finite
    return (unsigned short)(r >> 16);
}

// w_mix[b][co][tap][ci] = sum_k att[b][k] * w[k][co][ci][kh][kw], tap = kh*3+kw
__global__ __launch_bounds__(256) void mix_weights(
    const float* __restrict__ w, const float* __restrict__ att,
    unsigned short* __restrict__ wmix) {
    int idx = blockIdx.x * 256 + threadIdx.x;          // 32*64*9*64 = 1,179,648
    if (idx >= BATCH * DIM * 9 * DIM) return;
    int b   = idx / (DIM * 9 * DIM);
    int rem = idx - b * (DIM * 9 * DIM);
    int co  = rem / (9 * DIM);
    int k5  = rem - co * (9 * DIM);                    // tap*64 + ci
    int tap = k5 >> 6, ci = k5 & 63;
    float a0 = att[b*NK+0], a1 = att[b*NK+1], a2 = att[b*NK+2], a3 = att[b*NK+3];
    size_t base   = ((size_t)co * DIM + ci) * 9 + tap; // w[k][co][ci][tap]
    size_t stride = (size_t)DIM * DIM * 9;
    float s = a0*w[base] + a1*w[base+stride] + a2*w[base+2*stride] + a3*w[base+3*stride];
    wmix[idx] = f2bf(s);
}

__global__ __launch_bounds__(256) void mix_bias(
    const float* __restrict__ bias, const float* __restrict__ att,
    float* __restrict__ bmix) {
    int idx = blockIdx.x * 256 + threadIdx.x;          // 32*64 = 2048
    if (idx >= BATCH * DIM) return;
    int b = idx >> 6, co = idx & 63;
    float s = 0.f;
    for (int k = 0; k < NK; ++k) s += att[b*NK+k] * bias[k*DIM+co];
    bmix[idx] = s;
}

// Block = (sample b, 4 output rows, 64 output cols). 4 waves, wave = one output row,
// wave tile M=64 (all co) x N=64 cols. 9 taps x 2 K-steps of mfma_f32_16x16x32_bf16.
// Xs: [6 rows][66 cols][64 ci] bf16, ci-groups XOR-swizzled by (c&7) -> ds_read_b128,
// ~conflict-free. Ws: [64 co][64 ci] bf16, groups XOR-swizzled by (co&7).
__global__ __launch_bounds__(256, 2) void conv_mfma(
    const float* __restrict__ x, const unsigned short* __restrict__ wmix,
    const float* __restrict__ bmix, float* __restrict__ out) {

    __shared__ unsigned short Xs[6 * 66 * 64];   // 50,688 B
    __shared__ unsigned short Ws[64 * 64];       //  8,192 B  (total 58,880 -> 2 blocks/CU)

    int bid = blockIdx.x;
    int b   = bid >> 6;                          // 64 blocks per sample
    int r6  = bid & 63;
    int h0  = (r6 >> 1) * 4;                     // 32 row-groups
    int w0  = (r6 & 1) * 64;                     // 2 col halves

    int tid  = threadIdx.x;
    int wave = tid >> 6, lane = tid & 63;
    int l15  = lane & 15, q = lane >> 4;

    // ---- stage X tile: input rows h0-1..h0+4, cols w0-1..w0+64, all ci, fp32->bf16
    // main cols c=1..64 (win = w0+lane): coalesced 256B global loads per wave
    for (int j = wave; j < 384; j += 4) {        // 6 rows * 64 ci
        int ci = j & 63, r = j >> 6;
        int hin = h0 - 1 + r;
        float v = 0.f;
        if (hin >= 0 && hin < HH)
            v = x[(((size_t)b * DIM + ci) * HH + hin) * WW + (w0 + lane)];
        int c = lane + 1;
        Xs[(r * 66 + c) * 64 + ((((ci >> 3) ^ (c & 7))) << 3) + (ci & 7)] = f2bf(v);
    }
    // edge cols c=0 (win=w0-1) and c=65 (win=w0+64)
    for (int e = tid; e < 768; e += 256) {
        int edge = (e >= 384) ? 1 : 0;
        int j = e - edge * 384;
        int ci = j & 63, r = j >> 6;
        int hin = h0 - 1 + r;
        int win = edge ? (w0 + 64) : (w0 - 1);
        float v = 0.f;
        if (hin >= 0 && hin < HH && win >= 0 && win < WW)
            v = x[(((size_t)b * DIM + ci) * HH + hin) * WW + win];
        int c = edge ? 65 : 0;
        Xs[(r * 66 + c) * 64 + (((ci >> 3) ^ (c & 7)) << 3) + (ci & 7)] = f2bf(v);
    }

    // per-lane bias values for epilogue: co = mt*16 + q*4 + rg
    float biasr[4][4];
    for (int mt = 0; mt < 4; ++mt)
        for (int rg = 0; rg < 4; ++rg)
            biasr[mt][rg] = bmix[b * DIM + mt * 16 + q * 4 + rg];

    f32x4 acc[4][4];
    f32x4 zero = {0.f, 0.f, 0.f, 0.f};
    for (int mt = 0; mt < 4; ++mt)
        for (int nt = 0; nt < 4; ++nt) acc[mt][nt] = zero;

    for (int tap = 0; tap < 9; ++tap) {
        __syncthreads();                         // prev tap's Ws reads done (also fences Xs stage on tap 0... fenced below)
        // stage Ws[co][ci] = wmix[b][co][tap][ci], swizzled: 512 ushort8 chunks
        for (int ch = tid; ch < 512; ch += 256) {
            int co = ch >> 3, gp = ch & 7;
            int g = gp ^ (co & 7);
            const ushort8* src = (const ushort8*)&wmix[(((size_t)b * DIM + co) * 9 + tap) * 64 + g * 8];
            *(ushort8*)&Ws[co * 64 + gp * 8] = *src;
        }
        __syncthreads();

        int kh = tap / 3, kw = tap - kh * 3;
        int r = wave + kh;                       // staged input row index for this wave's output row
        for (int s = 0; s < 2; ++s) {
            int g = s * 4 + q;                   // logical ci-group = (32s + 8q)/8
            bf16x8 af[4], bfr[4];
            for (int mt = 0; mt < 4; ++mt) {
                int co = mt * 16 + l15;          // A[m=lane&15][k=quad*8+j]
                af[mt] = *(const bf16x8*)&Ws[co * 64 + ((g ^ (co & 7)) << 3)];
            }
            for (int nt = 0; nt < 4; ++nt) {
                int c = nt * 16 + l15 + kw;      // B[k=quad*8+j][n=lane&15]; input col = w + kw - 1
                bfr[nt] = *(const bf16x8*)&Xs[(r * 66 + c) * 64 + ((g ^ (c & 7)) << 3)];
            }
            for (int mt = 0; mt < 4; ++mt)
                for (int nt = 0; nt < 4; ++nt)
                    acc[mt][nt] = __builtin_amdgcn_mfma_f32_16x16x32_bf16(
                        af[mt], bfr[nt], acc[mt][nt], 0, 0, 0);
        }
    }

    // epilogue: C/D layout col=lane&15 (w), row=quad*4+reg (co)
    int h = h0 + wave;
    for (int mt = 0; mt < 4; ++mt) {
        for (int nt = 0; nt < 4; ++nt) {
            int wcol = w0 + nt * 16 + l15;
            for (int rg = 0; rg < 4; ++rg) {
                int co = mt * 16 + q * 4 + rg;
                out[(((size_t)b * DIM + co) * HH + h) * WW + wcol] = acc[mt][nt][rg] + biasr[mt][rg];
            }
        }
    }
}

extern "C" void kernel_launch(void* const* d_in, const int* in_sizes, int n_in,
                              void* d_out, int out_size, void* d_ws, size_t ws_size,
                              hipStream_t stream) {
    const float* x   = (const float*)d_in[0];
    const float* att = (const float*)d_in[1];
    const float* wgt = (const float*)d_in[2];
    const float* bia = (const float*)d_in[3];
    float* out = (float*)d_out;

    unsigned short* wmix = (unsigned short*)d_ws;            // 2,359,296 B
    float* bmix = (float*)((char*)d_ws + 2359296);           //     8,192 B

    mix_weights<<<4608, 256, 0, stream>>>(wgt, att, wmix);
    mix_bias<<<8, 256, 0, stream>>>(bia, att, bmix);
    conv_mfma<<<2048, 256, 0, stream>>>(x, wmix, bmix, out);
}

// Round 2
// 261.548 us; speedup vs baseline: 1.6505x; 1.6505x over previous
//
#include <hip/hip_runtime.h>

// KernelAggregation: per-sample mixed 3x3 SAME conv, implicit GEMM via bf16 MFMA.
// ws: [0, 2359296) = wmix bf16 [32][9 taps][64 co][64 ci]; [2359296, +8192) = bmix f32 [32][64].

#define DIM 64
#define BATCH 32
#define HH 128
#define WW 128
#define NK 4

typedef __attribute__((ext_vector_type(4))) float f32x4;
typedef __attribute__((ext_vector_type(8))) short bf16x8;
typedef __attribute__((ext_vector_type(8))) unsigned short ushort8;

static __device__ __forceinline__ unsigned short f2bf(float f) {
    union { float f; unsigned u; } v; v.f = f;
    unsigned r = v.u + 0x7fffu + ((v.u >> 16) & 1u);   // RNE, inputs finite
    return (unsigned short)(r >> 16);
}

// One wave per (b, co): coalesced read of w[k][co][ci][kh][kw] (576 contiguous
// floats per k), mix over k in registers, LDS transpose (ci,tap)->(tap,ci),
// coalesced bf16 write to wmix[b][tap][co][ci].
__global__ __launch_bounds__(256) void mix_weights(
    const float* __restrict__ w, const float* __restrict__ att,
    unsigned short* __restrict__ wmix) {
    __shared__ float tr[4][576];
    int wave = threadIdx.x >> 6, lane = threadIdx.x & 63;
    int idx = blockIdx.x * 4 + wave;               // 2048 (b,co) pairs
    int b = idx >> 6, co = idx & 63;
    float a[NK];
    #pragma unroll
    for (int k = 0; k < NK; ++k) a[k] = att[b * NK + k];
    float s[9];
    #pragma unroll
    for (int t = 0; t < 9; ++t) s[t] = 0.f;
    #pragma unroll
    for (int k = 0; k < NK; ++k) {
        const float* wp = w + (size_t)(k * DIM + co) * 576;
        #pragma unroll
        for (int t = 0; t < 9; ++t)
            s[t] += a[k] * wp[t * 64 + lane];      // element e = t*64+lane = ci*9+tap
    }
    #pragma unroll
    for (int t = 0; t < 9; ++t) tr[wave][t * 64 + lane] = s[t];
    __syncthreads();
    #pragma unroll
    for (int t = 0; t < 9; ++t) {
        // output element (tap=t, ci=lane)  <-  input element e = lane*9 + t
        float v = tr[wave][lane * 9 + t];
        wmix[(((size_t)b * 9 + t) * DIM + co) * DIM + lane] = f2bf(v);
    }
}

__global__ __launch_bounds__(256) void mix_bias(
    const float* __restrict__ bias, const float* __restrict__ att,
    float* __restrict__ bmix) {
    int idx = blockIdx.x * 256 + threadIdx.x;      // 2048
    if (idx >= BATCH * DIM) return;
    int b = idx >> 6, co = idx & 63;
    float s = 0.f;
    for (int k = 0; k < NK; ++k) s += att[b * NK + k] * bias[k * DIM + co];
    bmix[idx] = s;
}

// Block = (sample b, 4 output rows, 64 output cols). 4 waves; wave = one output
// row, tile M=64 co x N=64 cols, 9 taps x 2 K-steps of mfma_f32_16x16x32_bf16.
// Xs[r][c][ci] bf16, ci-group swizzled by (c>>1)&7 (reads 2-way=free, stage
// writes 4-way). Ws double-buffered 8KB/tap, weights register-prefetched 2 taps
// ahead -> one barrier per tap, no global latency inside the loop.
__global__ __launch_bounds__(256, 2) void conv_mfma(
    const float* __restrict__ x, const unsigned short* __restrict__ wmix,
    const float* __restrict__ bmix, float* __restrict__ out) {

    __shared__ unsigned short Xs[6 * 66 * 64];     // 50,688 B
    __shared__ unsigned short Ws[2][64 * 64];      // 16,384 B (total 67,072 -> 2 blocks/CU)

    int bid = blockIdx.x;
    int b   = bid >> 6;
    int r6  = bid & 63;
    int h0  = (r6 >> 1) * 4;
    int w0  = (r6 & 1) * 64;

    int tid  = threadIdx.x;
    int wave = tid >> 6, lane = tid & 63;
    int l15  = lane & 15, q = lane >> 4;

    // ---- weight chunk assignment (2 x 16B per thread per tap)
    const int ch0 = tid, ch1 = tid + 256;
    const int co0 = ch0 >> 3, gp0 = ch0 & 7;
    const int co1 = ch1 >> 3, gp1 = ch1 & 7;
    const unsigned short* wsA = wmix + (size_t)b * 9 * 4096 + co0 * 64 + ((gp0 ^ (co0 & 7)) << 3);
    const unsigned short* wsB = wmix + (size_t)b * 9 * 4096 + co1 * 64 + ((gp1 ^ (co1 & 7)) << 3);
    ushort8 wr0 = *(const ushort8*)(wsA);          // tap 0
    ushort8 wr1 = *(const ushort8*)(wsB);

    // ---- per-lane bias for epilogue (issue early)
    float biasr[4][4];
    #pragma unroll
    for (int mt = 0; mt < 4; ++mt)
        #pragma unroll
        for (int rg = 0; rg < 4; ++rg)
            biasr[mt][rg] = bmix[b * DIM + mt * 16 + q * 4 + rg];

    // ---- stage X: rows hin = h0-1 .. h0+4, cols w0..w0+63 via float4, batched
    #pragma unroll
    for (int half = 0; half < 2; ++half) {
        f32x4 xv[3][4];
        #pragma unroll
        for (int rr = 0; rr < 3; ++rr) {
            int r = half * 3 + rr;
            int hin = h0 - 1 + r;
            bool ok = (hin >= 0) && (hin < HH);    // wave-uniform
            #pragma unroll
            for (int it = 0; it < 4; ++it) {
                int lin = it * 256 + tid;
                int ci = lin >> 4, c4 = lin & 15;
                f32x4 v = {0.f, 0.f, 0.f, 0.f};
                if (ok)
                    v = *(const f32x4*)&x[(((size_t)b * DIM + ci) * HH + hin) * WW + w0 + c4 * 4];
                xv[rr][it] = v;
            }
        }
        #pragma unroll
        for (int rr = 0; rr < 3; ++rr) {
            int r = half * 3 + rr;
            #pragma unroll
            for (int it = 0; it < 4; ++it) {
                int lin = it * 256 + tid;
                int ci = lin >> 4, c4 = lin & 15;
                #pragma unroll
                for (int j = 0; j < 4; ++j) {
                    int c = c4 * 4 + 1 + j;
                    Xs[(r * 66 + c) * 64 + (((ci >> 3) ^ ((c >> 1) & 7)) << 3) + (ci & 7)] =
                        f2bf(xv[rr][it][j]);
                }
            }
        }
    }
    // edge cols c=0 (win=w0-1) and c=65 (win=w0+64): 768 items, 3/thread
    #pragma unroll
    for (int e = 0; e < 3; ++e) {
        int item = e * 256 + tid;
        int edge = item >= 384;
        int jj = item - edge * 384;
        int ci = jj & 63, r = jj >> 6;
        int hin = h0 - 1 + r;
        int win = edge ? (w0 + 64) : (w0 - 1);
        float v = 0.f;
        if (hin >= 0 && hin < HH && win >= 0 && win < WW)
            v = x[(((size_t)b * DIM + ci) * HH + hin) * WW + win];
        int c = edge ? 65 : 0;
        Xs[(r * 66 + c) * 64 + (((ci >> 3) ^ ((c >> 1) & 7)) << 3) + (ci & 7)] = f2bf(v);
    }

    // tap0 weights -> Ws[0]; prefetch tap1
    *(ushort8*)&Ws[0][co0 * 64 + gp0 * 8] = wr0;
    *(ushort8*)&Ws[0][co1 * 64 + gp1 * 8] = wr1;
    wr0 = *(const ushort8*)(wsA + 4096);
    wr1 = *(const ushort8*)(wsB + 4096);

    f32x4 acc[4][4];
    f32x4 zero = {0.f, 0.f, 0.f, 0.f};
    #pragma unroll
    for (int mt = 0; mt < 4; ++mt)
        #pragma unroll
        for (int nt = 0; nt < 4; ++nt) acc[mt][nt] = zero;

    __syncthreads();                               // Xs + Ws[0] visible

    #pragma unroll
    for (int tap = 0; tap < 9; ++tap) {
        int buf = tap & 1;
        if (tap < 8) {                             // stage tap+1 into other buffer
            *(ushort8*)&Ws[buf ^ 1][co0 * 64 + gp0 * 8] = wr0;
            *(ushort8*)&Ws[buf ^ 1][co1 * 64 + gp1 * 8] = wr1;
            if (tap < 7) {                         // prefetch tap+2
                wr0 = *(const ushort8*)(wsA + (tap + 2) * 4096);
                wr1 = *(const ushort8*)(wsB + (tap + 2) * 4096);
            }
        }
        int kh = tap / 3, kw = tap - kh * 3;
        int r = wave + kh;
        #pragma unroll
        for (int s = 0; s < 2; ++s) {
            int g = s * 4 + q;                     // logical ci-group: k = s*32 + q*8 + j
            bf16x8 af[4], bfr[4];
            #pragma unroll
            for (int mt = 0; mt < 4; ++mt) {
                int co = mt * 16 + l15;            // A[m=lane&15][k=quad*8+j]
                af[mt] = *(const bf16x8*)&Ws[buf][co * 64 + ((g ^ (co & 7)) << 3)];
            }
            #pragma unroll
            for (int nt = 0; nt < 4; ++nt) {
                int c = nt * 16 + l15 + kw;        // B[k][n=lane&15]
                bfr[nt] = *(const bf16x8*)&Xs[(r * 66 + c) * 64 + ((g ^ ((c >> 1) & 7)) << 3)];
            }
            #pragma unroll
            for (int mt = 0; mt < 4; ++mt)
                #pragma unroll
                for (int nt = 0; nt < 4; ++nt)
                    acc[mt][nt] = __builtin_amdgcn_mfma_f32_16x16x32_bf16(
                        af[mt], bfr[nt], acc[mt][nt], 0, 0, 0);
        }
        __syncthreads();
    }

    // epilogue: C/D layout col=lane&15 (w), row=quad*4+reg (co)
    int h = h0 + wave;
    #pragma unroll
    for (int mt = 0; mt < 4; ++mt) {
        #pragma unroll
        for (int nt = 0; nt < 4; ++nt) {
            int wcol = w0 + nt * 16 + l15;
            #pragma unroll
            for (int rg = 0; rg < 4; ++rg) {
                int co = mt * 16 + q * 4 + rg;
                out[(((size_t)b * DIM + co) * HH + h) * WW + wcol] = acc[mt][nt][rg] + biasr[mt][rg];
            }
        }
    }
}

extern "C" void kernel_launch(void* const* d_in, const int* in_sizes, int n_in,
                              void* d_out, int out_size, void* d_ws, size_t ws_size,
                              hipStream_t stream) {
    const float* x   = (const float*)d_in[0];
    const float* att = (const float*)d_in[1];
    const float* wgt = (const float*)d_in[2];
    const float* bia = (const float*)d_in[3];
    float* out = (float*)d_out;

    unsigned short* wmix = (unsigned short*)d_ws;            // 2,359,296 B
    float* bmix = (float*)((char*)d_ws + 2359296);           //     8,192 B

    mix_weights<<<512, 256, 0, stream>>>(wgt, att, wmix);
    mix_bias<<<8, 256, 0, stream>>>(bia, att, bmix);
    conv_mfma<<<2048, 256, 0, stream>>>(x, wmix, bmix, out);
}